// Round 3
// baseline (5514.328 us; speedup 1.0000x reference)
//
#include <hip/hip_runtime.h>
#include <hip/hip_bf16.h>

typedef __hip_bfloat16 bf16;

#define BB 4
#define SS 2048
#define DD 1024
#define HH 16
#define FF 4096
#define HD 64
#define LN_EPS 1e-5f

__device__ __forceinline__ float cvt(float v) { return v; }
__device__ __forceinline__ float cvt(bf16 v) { return __bfloat162float(v); }

__device__ __forceinline__ void stf(float* p, float v) { *p = v; }
__device__ __forceinline__ void stf(bf16* p, float v) { *p = __float2bfloat16(v); }

// ---------------------------------------------------------------------------
// Generic tiled GEMM: C(MxN) = A(MxK) @ B(KxN), fp32 accumulate.
// BLAY 0: B is natural (K,N) row-major.
// BLAY 1: B is (H, K, 64) per-head weight (n = h*64+e); requires 64-aligned n0.
// EPI 0: C = gemm                         (QKV)
// EPI 1: C = gemm + res (fp32)            (attn @ Wo + x)
// EPI 2: C = relu(gemm + bias)            (FFN1)
// EPI 3: C = gemm + bias + res (fp32)     (FFN2 + residual; in-place-safe)
// ---------------------------------------------------------------------------
template <typename TA, typename TB, typename TC, int BLAY, int EPI>
__launch_bounds__(256)
__global__ void gemm_kernel(const TA* __restrict__ A, const TB* __restrict__ Bm,
                            TC* __restrict__ C,
                            const float* __restrict__ bias,
                            const float* __restrict__ res,
                            int M, int N, int K) {
    __shared__ float As[16][64];
    __shared__ float Bs[16][64];

    const int tid = threadIdx.x;
    const int tx = tid & 15, ty = tid >> 4;
    const int m0 = blockIdx.y * 64, n0 = blockIdx.x * 64;

    float acc[4][4] = {};

    for (int k0 = 0; k0 < K; k0 += 16) {
        // Load A tile (64 rows x 16 k)
        {
            const int ml = tid >> 2, kl = (tid & 3) * 4;
            const TA* ap = A + (size_t)(m0 + ml) * K + k0 + kl;
#pragma unroll
            for (int j = 0; j < 4; ++j) As[kl + j][ml] = cvt(ap[j]);
        }
        // Load B tile (16 k x 64 n)
        {
            const int kl = tid >> 4, nl = (tid & 15) * 4;
            size_t base;
            if (BLAY == 0)
                base = (size_t)(k0 + kl) * N + n0 + nl;
            else
                base = ((size_t)((n0 + nl) >> 6) * K + (k0 + kl)) * 64 + ((n0 + nl) & 63);
#pragma unroll
            for (int j = 0; j < 4; ++j) Bs[kl][nl + j] = cvt(Bm[base + j]);
        }
        __syncthreads();
#pragma unroll
        for (int k = 0; k < 16; ++k) {
            float ar[4], br[4];
#pragma unroll
            for (int i = 0; i < 4; ++i) ar[i] = As[k][ty * 4 + i];
#pragma unroll
            for (int j = 0; j < 4; ++j) br[j] = Bs[k][tx * 4 + j];
#pragma unroll
            for (int i = 0; i < 4; ++i)
#pragma unroll
                for (int j = 0; j < 4; ++j) acc[i][j] += ar[i] * br[j];
        }
        __syncthreads();
    }

#pragma unroll
    for (int i = 0; i < 4; ++i) {
        const int m = m0 + ty * 4 + i;
#pragma unroll
        for (int j = 0; j < 4; ++j) {
            const int n = n0 + tx * 4 + j;
            float v = acc[i][j];
            if (EPI == 1) v += res[(size_t)m * N + n];
            if (EPI == 2) { v += bias[n]; v = fmaxf(v, 0.0f); }
            if (EPI == 3) { v += bias[n] + res[(size_t)m * N + n]; }
            stf(&C[(size_t)m * N + n], v);
        }
    }
}

// ---------------------------------------------------------------------------
// Flash attention (causal), bf16 Q/K/V in (B*S, D) layout (col = h*64 + e).
// One block: 32 query rows of one (b,h). Online softmax; O in registers.
// O is written in CONTIGUOUS (B, H, S, 64) layout: the reference does a
// plain .view of contiguous (B,H,S,hd) to (B,S,H*hd), so the Wo GEMM must
// read exactly this buffer as (B*S, D) row-major — no per-head interleave.
// ---------------------------------------------------------------------------
__launch_bounds__(256)
__global__ void attn_kernel(const bf16* __restrict__ Q, const bf16* __restrict__ Kb,
                            const bf16* __restrict__ V, bf16* __restrict__ O) {
    const int blk = blockIdx.x;
    const int qt = blk & 63;          // S/32 = 64 q-tiles
    const int h = (blk >> 6) & 15;
    const int b = blk >> 10;
    const int tid = threadIdx.x;
    const int q0 = qt * 32;

    __shared__ float Qs[32][65];
    __shared__ float Ks[32][65];
    __shared__ float Vs[32][65];
    __shared__ float Ps[32][33];
    __shared__ float mS[32], lS[32], aS[32];

    const size_t rowbase = (size_t)b * SS * DD + h * HD;

    for (int i = tid; i < 32 * 64; i += 256) {
        const int r = i >> 6, e = i & 63;
        Qs[r][e] = cvt(Q[rowbase + (size_t)(q0 + r) * DD + e]);
    }
    if (tid < 32) { mS[tid] = -1e30f; lS[tid] = 0.0f; }

    float oacc[8] = {};
    const int r_o = tid >> 3, e0 = (tid & 7) * 8;
    const int r_s = tid >> 3, c0 = (tid & 7) * 4;
    __syncthreads();

    for (int kt = 0; kt <= qt; ++kt) {
        const int t0 = kt * 32;
        for (int i = tid; i < 32 * 64; i += 256) {
            const int r = i >> 6, e = i & 63;
            Ks[r][e] = cvt(Kb[rowbase + (size_t)(t0 + r) * DD + e]);
            Vs[r][e] = cvt(V[rowbase + (size_t)(t0 + r) * DD + e]);
        }
        __syncthreads();

        // scores: row r_s, keys c0..c0+3
        float sc[4] = {};
        for (int d = 0; d < 64; ++d) {
            const float qv = Qs[r_s][d];
#pragma unroll
            for (int j = 0; j < 4; ++j) sc[j] += qv * Ks[c0 + j][d];
        }
#pragma unroll
        for (int j = 0; j < 4; ++j) {
            float s = sc[j] * 0.125f;  // 1/sqrt(64)
            if (kt == qt && (t0 + c0 + j) > (q0 + r_s)) s = -1e30f;
            Ps[r_s][c0 + j] = s;
        }
        __syncthreads();

        if (tid < 32) {
            const int r = tid;
            const float mold = mS[r];
            float mnew = mold;
            for (int c = 0; c < 32; ++c) mnew = fmaxf(mnew, Ps[r][c]);
            const float al = __expf(mold - mnew);
            float ls = 0.0f;
            for (int c = 0; c < 32; ++c) {
                const float p = __expf(Ps[r][c] - mnew);
                Ps[r][c] = p;
                ls += p;
            }
            lS[r] = lS[r] * al + ls;
            mS[r] = mnew;
            aS[r] = al;
        }
        __syncthreads();

        const float al = aS[r_o];
#pragma unroll
        for (int j = 0; j < 8; ++j) oacc[j] *= al;
        for (int c = 0; c < 32; ++c) {
            const float p = Ps[r_o][c];
#pragma unroll
            for (int j = 0; j < 8; ++j) oacc[j] += p * Vs[c][e0 + j];
        }
        __syncthreads();
    }

    const float linv = 1.0f / lS[r_o];
    // Contiguous (B,H,S,64) layout == reference's reshape semantics.
    const size_t obase = ((size_t)(b * HH + h) * SS + (q0 + r_o)) * HD;
#pragma unroll
    for (int j = 0; j < 8; ++j)
        stf(&O[obase + e0 + j], oacc[j] * linv);
}

// ---------------------------------------------------------------------------
// LayerNorm over D=1024, one block (256 threads) per row. In-place safe.
// ---------------------------------------------------------------------------
template <typename TOUT>
__launch_bounds__(256)
__global__ void ln_kernel(const float* __restrict__ X, TOUT* __restrict__ Y,
                          const float* __restrict__ g, const float* __restrict__ be) {
    const int row = blockIdx.x;
    const int tid = threadIdx.x;
    __shared__ float red[256];

    const float* x = X + (size_t)row * DD;
    float v[4];
#pragma unroll
    for (int i = 0; i < 4; ++i) v[i] = x[tid * 4 + i];

    float s = v[0] + v[1] + v[2] + v[3];
    red[tid] = s;
    __syncthreads();
    for (int off = 128; off > 0; off >>= 1) {
        if (tid < off) red[tid] += red[tid + off];
        __syncthreads();
    }
    const float mu = red[0] * (1.0f / DD);
    __syncthreads();

    float s2 = 0.0f;
#pragma unroll
    for (int i = 0; i < 4; ++i) { const float d = v[i] - mu; s2 += d * d; }
    red[tid] = s2;
    __syncthreads();
    for (int off = 128; off > 0; off >>= 1) {
        if (tid < off) red[tid] += red[tid + off];
        __syncthreads();
    }
    const float rs = rsqrtf(red[0] * (1.0f / DD) + LN_EPS);

#pragma unroll
    for (int i = 0; i < 4; ++i) {
        const int n = tid * 4 + i;
        stf(&Y[(size_t)row * DD + n], (v[i] - mu) * rs * g[n] + be[n]);
    }
}

extern "C" void kernel_launch(void* const* d_in, const int* in_sizes, int n_in,
                              void* d_out, int out_size, void* d_ws, size_t ws_size,
                              hipStream_t stream) {
    const float* x = (const float*)d_in[0];
    const float* Wq = (const float*)d_in[1];
    const float* Wk = (const float*)d_in[2];
    const float* Wv = (const float*)d_in[3];
    const float* Wo = (const float*)d_in[4];
    const float* g1 = (const float*)d_in[5];
    const float* be1 = (const float*)d_in[6];
    const float* w_in = (const float*)d_in[7];
    const float* b_in = (const float*)d_in[8];
    const float* w_out = (const float*)d_in[9];
    const float* b_out = (const float*)d_in[10];
    const float* g2 = (const float*)d_in[11];
    const float* be2 = (const float*)d_in[12];
    float* out = (float*)d_out;

    // Workspace layout (bytes), peak 96 MiB:
    //   [0,16M)   Qb bf16        -> later overlaid by Hd
    //   [16,32M)  Kb bf16
    //   [32,48M)  Vb bf16
    //   [48,64M)  At bf16 (contiguous (B,H,S,64))
    //   [0,64M)   Hd bf16 (B*S*F) after Wo-GEMM consumed At
    //   [64,96M)  X1 fp32 (LN tensor, in-place LN1, FFN2 output)
    char* wsb = (char*)d_ws;
    bf16* Qb = (bf16*)(wsb);
    bf16* Kb = (bf16*)(wsb + 16u * 1024 * 1024);
    bf16* Vb = (bf16*)(wsb + 32u * 1024 * 1024);
    bf16* At = (bf16*)(wsb + 48u * 1024 * 1024);
    bf16* Hd = (bf16*)(wsb);
    float* X1 = (float*)(wsb + 64u * 1024 * 1024);
    (void)ws_size;

    const int M = BB * SS;  // 8192
    dim3 blk(256);

    // QKV projections (weight layout (H, D, 64)), fp32 in -> bf16 out
    gemm_kernel<float, float, bf16, 1, 0><<<dim3(DD / 64, M / 64), blk, 0, stream>>>(
        x, Wq, Qb, nullptr, nullptr, M, DD, DD);
    gemm_kernel<float, float, bf16, 1, 0><<<dim3(DD / 64, M / 64), blk, 0, stream>>>(
        x, Wk, Kb, nullptr, nullptr, M, DD, DD);
    gemm_kernel<float, float, bf16, 1, 0><<<dim3(DD / 64, M / 64), blk, 0, stream>>>(
        x, Wv, Vb, nullptr, nullptr, M, DD, DD);

    // Causal flash attention (bf16 in/out, fp32 math)
    attn_kernel<<<dim3(BB * HH * (SS / 32)), blk, 0, stream>>>(Qb, Kb, Vb, At);

    // attn(view) @ Wo + x  -> X1 fp32 (pre-LN)
    gemm_kernel<bf16, float, float, 0, 1><<<dim3(DD / 64, M / 64), blk, 0, stream>>>(
        At, Wo, X1, nullptr, x, M, DD, DD);
    // LN1 in-place (fp32)
    ln_kernel<float><<<dim3(M), blk, 0, stream>>>(X1, X1, g1, be1);

    // FFN1: relu(X1 @ w_in + b_in) -> Hd bf16
    gemm_kernel<float, float, bf16, 0, 2><<<dim3(FF / 64, M / 64), blk, 0, stream>>>(
        X1, w_in, Hd, b_in, nullptr, M, FF, DD);

    // FFN2: Hd @ w_out + b_out + X1 -> X1 (in-place, fp32)
    gemm_kernel<bf16, float, float, 0, 3><<<dim3(DD / 64, M / 64), blk, 0, stream>>>(
        Hd, w_out, X1, b_out, X1, M, DD, FF);

    // LN2 -> fp32 out
    ln_kernel<float><<<dim3(M), blk, 0, stream>>>(X1, out, g2, be2);
}

// Round 4
// 2856.356 us; speedup vs baseline: 1.9305x; 1.9305x over previous
//
#include <hip/hip_runtime.h>
#include <hip/hip_bf16.h>

typedef __hip_bfloat16 bf16;

#define BB 4
#define SS 2048
#define DD 1024
#define HH 16
#define FF 4096
#define HD 64
#define LN_EPS 1e-5f

typedef __attribute__((ext_vector_type(8))) __bf16 bf16x8;
typedef __attribute__((ext_vector_type(8))) unsigned short u16x8;
typedef __attribute__((ext_vector_type(4))) float f32x4;

__device__ __forceinline__ float cvt(float v) { return v; }
__device__ __forceinline__ float cvt(bf16 v) { return __bfloat162float(v); }

__device__ __forceinline__ void stf(float* p, float v) { *p = v; }
__device__ __forceinline__ void stf(bf16* p, float v) { *p = __float2bfloat16(v); }

// fp32 -> bf16 round-to-nearest-even (bit manipulation; no API dependency)
__device__ __forceinline__ unsigned short f2bf_rne(float x) {
    unsigned int u = __float_as_uint(x);
    unsigned int r = (u + 0x7fffu + ((u >> 16) & 1u)) >> 16;
    return (unsigned short)r;
}

// Load one 8-element chunk as bf16 bits (converting if source is fp32).
template <typename TA>
__device__ __forceinline__ u16x8 ld_chunk(const TA* p);

template <>
__device__ __forceinline__ u16x8 ld_chunk<bf16>(const bf16* p) {
    return *(const u16x8*)p;
}
template <>
__device__ __forceinline__ u16x8 ld_chunk<float>(const float* p) {
    const float4* q = (const float4*)p;
    const float4 a = q[0], b = q[1];
    u16x8 r;
    r[0] = f2bf_rne(a.x); r[1] = f2bf_rne(a.y); r[2] = f2bf_rne(a.z); r[3] = f2bf_rne(a.w);
    r[4] = f2bf_rne(b.x); r[5] = f2bf_rne(b.y); r[6] = f2bf_rne(b.z); r[7] = f2bf_rne(b.w);
    return r;
}

// ---------------------------------------------------------------------------
// MFMA GEMM: C(MxN) = A(MxK) @ B(KxN), with B supplied TRANSPOSED (N x K bf16).
// A is row-major (fp32 converted in staging, or bf16). fp32 accumulate.
// 128x128 tile, BK=64, 256 threads = 4 waves, each wave a 64x64 sub-tile as
// 4x4 grid of v_mfma_f32_16x16x32_bf16. LDS chunk layout XOR-swizzled:
//   LDS[row][c] = Global[row][c ^ (row&7)]   (chunks of 8 elems = 16B)
// -> ds_write lane-contiguous (conflict-free) and ds_read_b128 fragment reads
//    spread uniformly over all 32 banks (8 dwords/bank = minimum).
// EPI 0: C = gemm (bf16 out)          EPI 1: C = gemm + res (fp32 out)
// EPI 2: C = relu(gemm+bias) (bf16)   EPI 3: C = gemm + bias + res (fp32)
// ---------------------------------------------------------------------------
template <typename TA, typename TC, int EPI>
__launch_bounds__(256)
__global__ void mfma_gemm(const TA* __restrict__ A, const bf16* __restrict__ Bt,
                          TC* __restrict__ C, const float* __restrict__ bias,
                          const float* __restrict__ res, int M, int N, int K) {
    __shared__ unsigned short As[128 * 64];
    __shared__ unsigned short Bs[128 * 64];

    const int tid = threadIdx.x;
    const int lane = tid & 63;
    const int w = tid >> 6;
    const int wm = w >> 1, wn = w & 1;
    const int m0 = blockIdx.y * 128, n0 = blockIdx.x * 128;

    // staging map: 1024 chunks of 8 elems per matrix; 4 chunks/thread
    int fr[4], fc[4], fg[4];
#pragma unroll
    for (int i = 0; i < 4; ++i) {
        const int f = tid + i * 256;
        fr[i] = f >> 3;           // tile row (A: m, B: n)
        fc[i] = f & 7;            // LDS chunk slot
        fg[i] = fc[i] ^ (fr[i] & 7);  // global chunk fetched into that slot
    }

    f32x4 acc[4][4];
#pragma unroll
    for (int i = 0; i < 4; ++i)
#pragma unroll
        for (int j = 0; j < 4; ++j) acc[i][j] = (f32x4){0.f, 0.f, 0.f, 0.f};

    u16x8 sa[4], sb[4];
#pragma unroll
    for (int i = 0; i < 4; ++i) {
        sa[i] = ld_chunk<TA>(A + (size_t)(m0 + fr[i]) * K + fg[i] * 8);
        sb[i] = ld_chunk<bf16>(Bt + (size_t)(n0 + fr[i]) * K + fg[i] * 8);
    }

    for (int k0 = 0; k0 < K; k0 += 64) {
        if (k0 > 0) __syncthreads();
#pragma unroll
        for (int i = 0; i < 4; ++i) {
            *(u16x8*)&As[fr[i] * 64 + fc[i] * 8] = sa[i];
            *(u16x8*)&Bs[fr[i] * 64 + fc[i] * 8] = sb[i];
        }
        __syncthreads();
        if (k0 + 64 < K) {
            const int kn = k0 + 64;
#pragma unroll
            for (int i = 0; i < 4; ++i) {
                sa[i] = ld_chunk<TA>(A + (size_t)(m0 + fr[i]) * K + kn + fg[i] * 8);
                sb[i] = ld_chunk<bf16>(Bt + (size_t)(n0 + fr[i]) * K + kn + fg[i] * 8);
            }
        }
#pragma unroll
        for (int ks = 0; ks < 2; ++ks) {
            bf16x8 af[4], bfr[4];
#pragma unroll
            for (int i = 0; i < 4; ++i) {
                const int row = wm * 64 + i * 16 + (lane & 15);
                const int col = wn * 64 + i * 16 + (lane & 15);
                const int g = ks * 4 + (lane >> 4);
                af[i]  = *(const bf16x8*)&As[row * 64 + (g ^ (row & 7)) * 8];
                bfr[i] = *(const bf16x8*)&Bs[col * 64 + (g ^ (col & 7)) * 8];
            }
#pragma unroll
            for (int i = 0; i < 4; ++i)
#pragma unroll
                for (int j = 0; j < 4; ++j)
                    acc[i][j] = __builtin_amdgcn_mfma_f32_16x16x32_bf16(
                        af[i], bfr[j], acc[i][j], 0, 0, 0);
        }
    }

    // Epilogue. C/D layout (m89/m91-verified): col = lane&15, row = (lane>>4)*4 + reg.
#pragma unroll
    for (int i = 0; i < 4; ++i) {
        const int mrow0 = m0 + wm * 64 + i * 16 + (lane >> 4) * 4;
#pragma unroll
        for (int j = 0; j < 4; ++j) {
            const int n = n0 + wn * 64 + j * 16 + (lane & 15);
#pragma unroll
            for (int r = 0; r < 4; ++r) {
                const size_t idx = (size_t)(mrow0 + r) * N + n;
                float v = acc[i][j][r];
                if (EPI == 1) v += res[idx];
                if (EPI == 2) { v += bias[n]; v = fmaxf(v, 0.0f); }
                if (EPI == 3) v += bias[n] + res[idx];
                stf(&C[idx], v);
            }
        }
    }
}

// ---------------------------------------------------------------------------
// Tiled transpose fp32 (R x C, row-major) -> bf16 (C x R, row-major).
// blockIdx.z adds z*R*C to both base pointers (per-head transpose for Wq/Wk/Wv).
// ---------------------------------------------------------------------------
__launch_bounds__(256)
__global__ void tr_f32_bf16(const float* __restrict__ in, bf16* __restrict__ out,
                            int R, int C) {
    __shared__ float t[32][33];
    const size_t zo = (size_t)blockIdx.z * R * C;
    const int bx = blockIdx.x * 32;  // col base
    const int by = blockIdx.y * 32;  // row base
    const int tx = threadIdx.x & 31, ty = threadIdx.x >> 5;
#pragma unroll
    for (int i = 0; i < 32; i += 8)
        t[ty + i][tx] = in[zo + (size_t)(by + ty + i) * C + bx + tx];
    __syncthreads();
#pragma unroll
    for (int i = 0; i < 32; i += 8)
        out[zo + (size_t)(bx + ty + i) * R + by + tx] = __float2bfloat16(t[tx][ty + i]);
}

// ---------------------------------------------------------------------------
// Flash attention (causal), bf16 Q/K/V in (B*S, D) layout (col = h*64 + e).
// O written to contiguous (B,H,S,64) == reference's reshape semantics.
// (unchanged from R3 passing version)
// ---------------------------------------------------------------------------
__launch_bounds__(256)
__global__ void attn_kernel(const bf16* __restrict__ Q, const bf16* __restrict__ Kb,
                            const bf16* __restrict__ V, bf16* __restrict__ O) {
    const int blk = blockIdx.x;
    const int qt = blk & 63;
    const int h = (blk >> 6) & 15;
    const int b = blk >> 10;
    const int tid = threadIdx.x;
    const int q0 = qt * 32;

    __shared__ float Qs[32][65];
    __shared__ float Ks[32][65];
    __shared__ float Vs[32][65];
    __shared__ float Ps[32][33];
    __shared__ float mS[32], lS[32], aS[32];

    const size_t rowbase = (size_t)b * SS * DD + h * HD;

    for (int i = tid; i < 32 * 64; i += 256) {
        const int r = i >> 6, e = i & 63;
        Qs[r][e] = cvt(Q[rowbase + (size_t)(q0 + r) * DD + e]);
    }
    if (tid < 32) { mS[tid] = -1e30f; lS[tid] = 0.0f; }

    float oacc[8] = {};
    const int r_o = tid >> 3, e0 = (tid & 7) * 8;
    const int r_s = tid >> 3, c0 = (tid & 7) * 4;
    __syncthreads();

    for (int kt = 0; kt <= qt; ++kt) {
        const int t0 = kt * 32;
        for (int i = tid; i < 32 * 64; i += 256) {
            const int r = i >> 6, e = i & 63;
            Ks[r][e] = cvt(Kb[rowbase + (size_t)(t0 + r) * DD + e]);
            Vs[r][e] = cvt(V[rowbase + (size_t)(t0 + r) * DD + e]);
        }
        __syncthreads();

        float sc[4] = {};
        for (int d = 0; d < 64; ++d) {
            const float qv = Qs[r_s][d];
#pragma unroll
            for (int j = 0; j < 4; ++j) sc[j] += qv * Ks[c0 + j][d];
        }
#pragma unroll
        for (int j = 0; j < 4; ++j) {
            float s = sc[j] * 0.125f;
            if (kt == qt && (t0 + c0 + j) > (q0 + r_s)) s = -1e30f;
            Ps[r_s][c0 + j] = s;
        }
        __syncthreads();

        if (tid < 32) {
            const int r = tid;
            const float mold = mS[r];
            float mnew = mold;
            for (int c = 0; c < 32; ++c) mnew = fmaxf(mnew, Ps[r][c]);
            const float al = __expf(mold - mnew);
            float ls = 0.0f;
            for (int c = 0; c < 32; ++c) {
                const float p = __expf(Ps[r][c] - mnew);
                Ps[r][c] = p;
                ls += p;
            }
            lS[r] = lS[r] * al + ls;
            mS[r] = mnew;
            aS[r] = al;
        }
        __syncthreads();

        const float al = aS[r_o];
#pragma unroll
        for (int j = 0; j < 8; ++j) oacc[j] *= al;
        for (int c = 0; c < 32; ++c) {
            const float p = Ps[r_o][c];
#pragma unroll
            for (int j = 0; j < 8; ++j) oacc[j] += p * Vs[c][e0 + j];
        }
        __syncthreads();
    }

    const float linv = 1.0f / lS[r_o];
    const size_t obase = ((size_t)(b * HH + h) * SS + (q0 + r_o)) * HD;
#pragma unroll
    for (int j = 0; j < 8; ++j)
        stf(&O[obase + e0 + j], oacc[j] * linv);
}

// ---------------------------------------------------------------------------
// LayerNorm over D=1024, one block per row. In-place safe.
// ---------------------------------------------------------------------------
template <typename TOUT>
__launch_bounds__(256)
__global__ void ln_kernel(const float* __restrict__ X, TOUT* __restrict__ Y,
                          const float* __restrict__ g, const float* __restrict__ be) {
    const int row = blockIdx.x;
    const int tid = threadIdx.x;
    __shared__ float red[256];

    const float* x = X + (size_t)row * DD;
    float v[4];
#pragma unroll
    for (int i = 0; i < 4; ++i) v[i] = x[tid * 4 + i];

    float s = v[0] + v[1] + v[2] + v[3];
    red[tid] = s;
    __syncthreads();
    for (int off = 128; off > 0; off >>= 1) {
        if (tid < off) red[tid] += red[tid + off];
        __syncthreads();
    }
    const float mu = red[0] * (1.0f / DD);
    __syncthreads();

    float s2 = 0.0f;
#pragma unroll
    for (int i = 0; i < 4; ++i) { const float d = v[i] - mu; s2 += d * d; }
    red[tid] = s2;
    __syncthreads();
    for (int off = 128; off > 0; off >>= 1) {
        if (tid < off) red[tid] += red[tid + off];
        __syncthreads();
    }
    const float rs = rsqrtf(red[0] * (1.0f / DD) + LN_EPS);

#pragma unroll
    for (int i = 0; i < 4; ++i) {
        const int n = tid * 4 + i;
        stf(&Y[(size_t)row * DD + n], (v[i] - mu) * rs * g[n] + be[n]);
    }
}

extern "C" void kernel_launch(void* const* d_in, const int* in_sizes, int n_in,
                              void* d_out, int out_size, void* d_ws, size_t ws_size,
                              hipStream_t stream) {
    const float* x = (const float*)d_in[0];
    const float* Wq = (const float*)d_in[1];
    const float* Wk = (const float*)d_in[2];
    const float* Wv = (const float*)d_in[3];
    const float* Wo = (const float*)d_in[4];
    const float* g1 = (const float*)d_in[5];
    const float* be1 = (const float*)d_in[6];
    const float* w_in = (const float*)d_in[7];
    const float* b_in = (const float*)d_in[8];
    const float* w_out = (const float*)d_in[9];
    const float* b_out = (const float*)d_in[10];
    const float* g2 = (const float*)d_in[11];
    const float* be2 = (const float*)d_in[12];
    float* out = (float*)d_out;

    // Workspace (bytes), peak 120 MiB:
    //   [0,16M)    Qb bf16   -+
    //   [16,32M)   Kb bf16    |-> overlaid by Hd bf16 (B*S*F) after Wo-GEMM
    //   [32,48M)   Vb bf16    |
    //   [48,64M)   At bf16   -+   (contiguous (B,H,S,64))
    //   [64,96M)   X1 fp32 (LN tensor; in-place LN1; FFN2 output)
    //   [96,120M)  transposed bf16 weights: WqT WkT WvT WoT (2M each), w_inT(8M), w_outT(8M)
    char* wsb = (char*)d_ws;
    const size_t MiB = 1u << 20;
    bf16* Qb = (bf16*)(wsb);
    bf16* Kb = (bf16*)(wsb + 16 * MiB);
    bf16* Vb = (bf16*)(wsb + 32 * MiB);
    bf16* At = (bf16*)(wsb + 48 * MiB);
    bf16* Hd = (bf16*)(wsb);
    float* X1 = (float*)(wsb + 64 * MiB);
    bf16* WqT = (bf16*)(wsb + 96 * MiB);
    bf16* WkT = (bf16*)(wsb + 98 * MiB);
    bf16* WvT = (bf16*)(wsb + 100 * MiB);
    bf16* WoT = (bf16*)(wsb + 102 * MiB);
    bf16* w_inT = (bf16*)(wsb + 104 * MiB);
    bf16* w_outT = (bf16*)(wsb + 112 * MiB);
    (void)ws_size;

    const int M = BB * SS;  // 8192
    dim3 blk(256);

    // ---- Pre-transpose weights to bf16 N x K ----
    // Wq/Wk/Wv: per-head (D x 64) -> (64 x D); n = h*64+e rows
    tr_f32_bf16<<<dim3(2, 32, 16), blk, 0, stream>>>(Wq, WqT, DD, HD);
    tr_f32_bf16<<<dim3(2, 32, 16), blk, 0, stream>>>(Wk, WkT, DD, HD);
    tr_f32_bf16<<<dim3(2, 32, 16), blk, 0, stream>>>(Wv, WvT, DD, HD);
    tr_f32_bf16<<<dim3(32, 32, 1), blk, 0, stream>>>(Wo, WoT, DD, DD);
    tr_f32_bf16<<<dim3(128, 32, 1), blk, 0, stream>>>(w_in, w_inT, DD, FF);
    tr_f32_bf16<<<dim3(32, 128, 1), blk, 0, stream>>>(w_out, w_outT, FF, DD);

    // ---- QKV projections: x(fp32) @ W -> bf16 ----
    mfma_gemm<float, bf16, 0><<<dim3(DD / 128, M / 128), blk, 0, stream>>>(
        x, WqT, Qb, nullptr, nullptr, M, DD, DD);
    mfma_gemm<float, bf16, 0><<<dim3(DD / 128, M / 128), blk, 0, stream>>>(
        x, WkT, Kb, nullptr, nullptr, M, DD, DD);
    mfma_gemm<float, bf16, 0><<<dim3(DD / 128, M / 128), blk, 0, stream>>>(
        x, WvT, Vb, nullptr, nullptr, M, DD, DD);

    // ---- Causal flash attention ----
    attn_kernel<<<dim3(BB * HH * (SS / 32)), blk, 0, stream>>>(Qb, Kb, Vb, At);

    // ---- attn(view) @ Wo + x -> X1 fp32 ----
    mfma_gemm<bf16, float, 1><<<dim3(DD / 128, M / 128), blk, 0, stream>>>(
        At, WoT, X1, nullptr, x, M, DD, DD);
    ln_kernel<float><<<dim3(M), blk, 0, stream>>>(X1, X1, g1, be1);

    // ---- FFN1: relu(X1 @ w_in + b_in) -> Hd bf16 ----
    mfma_gemm<float, bf16, 2><<<dim3(FF / 128, M / 128), blk, 0, stream>>>(
        X1, w_inT, Hd, b_in, nullptr, M, FF, DD);

    // ---- FFN2: Hd @ w_out + b_out + X1 -> X1 (in-place) ----
    mfma_gemm<bf16, float, 3><<<dim3(DD / 128, M / 128), blk, 0, stream>>>(
        Hd, w_outT, X1, b_out, X1, M, DD, FF);

    // ---- LN2 -> fp32 out ----
    ln_kernel<float><<<dim3(M), blk, 0, stream>>>(X1, out, g2, be2);
}

// Round 5
// 625.371 us; speedup vs baseline: 8.8177x; 4.5675x over previous
//
#include <hip/hip_runtime.h>
#include <hip/hip_bf16.h>

typedef __hip_bfloat16 bf16;

#define BB 4
#define SS 2048
#define DD 1024
#define HH 16
#define FF 4096
#define HD 64
#define LN_EPS 1e-5f

typedef __attribute__((ext_vector_type(8))) __bf16 bf16x8;
typedef __attribute__((ext_vector_type(8))) unsigned short u16x8;
typedef __attribute__((ext_vector_type(4))) float f32x4;

__device__ __forceinline__ float cvt(float v) { return v; }
__device__ __forceinline__ float cvt(bf16 v) { return __bfloat162float(v); }

__device__ __forceinline__ void stf(float* p, float v) { *p = v; }
__device__ __forceinline__ void stf(bf16* p, float v) { *p = __float2bfloat16(v); }

// fp32 -> bf16 round-to-nearest-even
__device__ __forceinline__ unsigned short f2bf_rne(float x) {
    unsigned int u = __float_as_uint(x);
    unsigned int r = (u + 0x7fffu + ((u >> 16) & 1u)) >> 16;
    return (unsigned short)r;
}

template <typename TA>
__device__ __forceinline__ u16x8 ld_chunk(const TA* p);

template <>
__device__ __forceinline__ u16x8 ld_chunk<bf16>(const bf16* p) {
    return *(const u16x8*)p;
}
template <>
__device__ __forceinline__ u16x8 ld_chunk<float>(const float* p) {
    const float4* q = (const float4*)p;
    const float4 a = q[0], b = q[1];
    u16x8 r;
    r[0] = f2bf_rne(a.x); r[1] = f2bf_rne(a.y); r[2] = f2bf_rne(a.z); r[3] = f2bf_rne(a.w);
    r[4] = f2bf_rne(b.x); r[5] = f2bf_rne(b.y); r[6] = f2bf_rne(b.z); r[7] = f2bf_rne(b.w);
    return r;
}

// ---------------------------------------------------------------------------
// MFMA GEMM: C(MxN) = A(MxK) @ B(KxN), B supplied TRANSPOSED (N x K bf16).
// 128x128 tile, BK=64, 4 waves, 16x16x32 bf16 MFMA, XOR-swizzled LDS.
// EPI 0: C = gemm * oscale (bf16 out)   EPI 1: C = gemm + res (fp32 out)
// EPI 2: C = relu(gemm+bias) (bf16)     EPI 3: C = gemm + bias + res (fp32)
// EPI 4: bf16 TRANSPOSED write to VT(B*D, S):  VT[b*1024 + n][s] = C[m][n]
// ---------------------------------------------------------------------------
template <typename TA, typename TC, int EPI>
__launch_bounds__(256)
__global__ void mfma_gemm(const TA* __restrict__ A, const bf16* __restrict__ Bt,
                          TC* __restrict__ C, const float* __restrict__ bias,
                          const float* __restrict__ res, int M, int N, int K,
                          float oscale) {
    __shared__ unsigned short As[128 * 64];
    __shared__ unsigned short Bs[128 * 64];

    const int tid = threadIdx.x;
    const int lane = tid & 63;
    const int w = tid >> 6;
    const int wm = w >> 1, wn = w & 1;
    const int m0 = blockIdx.y * 128, n0 = blockIdx.x * 128;

    int fr[4], fc[4], fg[4];
#pragma unroll
    for (int i = 0; i < 4; ++i) {
        const int f = tid + i * 256;
        fr[i] = f >> 3;
        fc[i] = f & 7;
        fg[i] = fc[i] ^ (fr[i] & 7);
    }

    f32x4 acc[4][4];
#pragma unroll
    for (int i = 0; i < 4; ++i)
#pragma unroll
        for (int j = 0; j < 4; ++j) acc[i][j] = (f32x4){0.f, 0.f, 0.f, 0.f};

    u16x8 sa[4], sb[4];
#pragma unroll
    for (int i = 0; i < 4; ++i) {
        sa[i] = ld_chunk<TA>(A + (size_t)(m0 + fr[i]) * K + fg[i] * 8);
        sb[i] = ld_chunk<bf16>(Bt + (size_t)(n0 + fr[i]) * K + fg[i] * 8);
    }

    for (int k0 = 0; k0 < K; k0 += 64) {
        if (k0 > 0) __syncthreads();
#pragma unroll
        for (int i = 0; i < 4; ++i) {
            *(u16x8*)&As[fr[i] * 64 + fc[i] * 8] = sa[i];
            *(u16x8*)&Bs[fr[i] * 64 + fc[i] * 8] = sb[i];
        }
        __syncthreads();
        if (k0 + 64 < K) {
            const int kn = k0 + 64;
#pragma unroll
            for (int i = 0; i < 4; ++i) {
                sa[i] = ld_chunk<TA>(A + (size_t)(m0 + fr[i]) * K + kn + fg[i] * 8);
                sb[i] = ld_chunk<bf16>(Bt + (size_t)(n0 + fr[i]) * K + kn + fg[i] * 8);
            }
        }
#pragma unroll
        for (int ks = 0; ks < 2; ++ks) {
            bf16x8 af[4], bfr[4];
#pragma unroll
            for (int i = 0; i < 4; ++i) {
                const int row = wm * 64 + i * 16 + (lane & 15);
                const int col = wn * 64 + i * 16 + (lane & 15);
                const int g = ks * 4 + (lane >> 4);
                af[i]  = *(const bf16x8*)&As[row * 64 + (g ^ (row & 7)) * 8];
                bfr[i] = *(const bf16x8*)&Bs[col * 64 + (g ^ (col & 7)) * 8];
            }
#pragma unroll
            for (int i = 0; i < 4; ++i)
#pragma unroll
                for (int j = 0; j < 4; ++j)
                    acc[i][j] = __builtin_amdgcn_mfma_f32_16x16x32_bf16(
                        af[i], bfr[j], acc[i][j], 0, 0, 0);
        }
    }

    // Epilogue. C/D layout: col = lane&15, row = (lane>>4)*4 + reg.
#pragma unroll
    for (int i = 0; i < 4; ++i) {
        const int mrow0 = m0 + wm * 64 + i * 16 + (lane >> 4) * 4;
#pragma unroll
        for (int j = 0; j < 4; ++j) {
            const int n = n0 + wn * 64 + j * 16 + (lane & 15);
            if (EPI == 4) {
                // VT[(b*1024 + n)][s], s = mrow0&2047 contiguous over regs
                const int bb = mrow0 >> 11, s = mrow0 & 2047;
                ushort4 pk;
                pk.x = f2bf_rne(acc[i][j][0]);
                pk.y = f2bf_rne(acc[i][j][1]);
                pk.z = f2bf_rne(acc[i][j][2]);
                pk.w = f2bf_rne(acc[i][j][3]);
                *(ushort4*)((unsigned short*)C + ((size_t)bb * 1024 + n) * SS + s) = pk;
            } else {
#pragma unroll
                for (int r = 0; r < 4; ++r) {
                    const size_t idx = (size_t)(mrow0 + r) * N + n;
                    float v = acc[i][j][r];
                    if (EPI == 0) v *= oscale;
                    if (EPI == 1) v += res[idx];
                    if (EPI == 2) { v += bias[n]; v = fmaxf(v, 0.0f); }
                    if (EPI == 3) v += bias[n] + res[idx];
                    stf(&C[idx], v);
                }
            }
        }
    }
}

// ---------------------------------------------------------------------------
// Tiled transpose fp32 (R x C) -> bf16 (C x R). blockIdx.z: per-head offset.
// ---------------------------------------------------------------------------
__launch_bounds__(256)
__global__ void tr_f32_bf16(const float* __restrict__ in, bf16* __restrict__ out,
                            int R, int C) {
    __shared__ float t[32][33];
    const size_t zo = (size_t)blockIdx.z * R * C;
    const int bx = blockIdx.x * 32;
    const int by = blockIdx.y * 32;
    const int tx = threadIdx.x & 31, ty = threadIdx.x >> 5;
#pragma unroll
    for (int i = 0; i < 32; i += 8)
        t[ty + i][tx] = in[zo + (size_t)(by + ty + i) * C + bx + tx];
    __syncthreads();
#pragma unroll
    for (int i = 0; i < 32; i += 8)
        out[zo + (size_t)(bx + ty + i) * R + by + tx] = __float2bfloat16(t[tx][ty + i]);
}

// ---------------------------------------------------------------------------
// MFMA causal flash attention.
// Q, K: bf16 (B*S, D), col = h*64+e. Q pre-scaled by 1/8.
// VT: bf16 (B*D, S): row b*1024 + h*64 + e, col s (written by EPI-4 V-GEMM).
// O: bf16 contiguous (B,H,S,64).
// Block: 64 Q-rows of one (b,h); 4 waves x 16 rows. K-tiles of 64 keys.
// Softmax state in registers (C-layout row = quad*4+r); row-reduce via
// __shfl_xor over the 16-lane col group. P: C-layout -> LDS (stride 72)
// -> A-layout b128 reads (m120 pattern).
// ---------------------------------------------------------------------------
__launch_bounds__(256, 4)
__global__ void attn_mfma(const bf16* __restrict__ Q, const bf16* __restrict__ K,
                          const bf16* __restrict__ VT, bf16* __restrict__ O) {
    __shared__ unsigned short Ks[64 * 72];
    __shared__ unsigned short Vs[64 * 72];
    __shared__ unsigned short Ps[64 * 72];

    const int tid = threadIdx.x;
    const int lane = tid & 63;
    const int w = tid >> 6;
    const int ln = lane & 15;
    const int qd = lane >> 4;
    const int bh = blockIdx.x;
    const int b = bh >> 4;
    const int h = bh & 15;
    const int qi = 31 - blockIdx.y;  // heavy blocks dispatch first
    const int q0 = qi * 64;

    // Q fragments (A-layout): row w*16+ln, k contiguous. Held all kernel.
    bf16x8 aq[2];
    {
        const unsigned short* qp =
            (const unsigned short*)Q + ((size_t)b * SS + q0 + w * 16 + ln) * DD + h * HD;
#pragma unroll
        for (int ks = 0; ks < 2; ++ks)
            aq[ks] = *(const bf16x8*)(qp + ks * 32 + qd * 8);
    }

    // staging: 2 chunks per thread per matrix (64 rows x 8 chunks of 16B)
    int sr[2], sc[2];
#pragma unroll
    for (int i = 0; i < 2; ++i) {
        const int f = tid + i * 256;
        sr[i] = f >> 3;
        sc[i] = f & 7;
    }
    const unsigned short* kbase = (const unsigned short*)K + (size_t)b * SS * DD + h * HD;
    const unsigned short* vbase = (const unsigned short*)VT + (size_t)(b * DD + h * HD) * SS;

    u16x8 kpre[2], vpre[2];
#pragma unroll
    for (int i = 0; i < 2; ++i) {
        kpre[i] = *(const u16x8*)(kbase + (size_t)sr[i] * DD + sc[i] * 8);
        vpre[i] = *(const u16x8*)(vbase + (size_t)sr[i] * SS + sc[i] * 8);
    }

    f32x4 oacc[4];
#pragma unroll
    for (int e = 0; e < 4; ++e) oacc[e] = (f32x4){0.f, 0.f, 0.f, 0.f};
    float m_r[4] = {-1e30f, -1e30f, -1e30f, -1e30f};
    float l_r[4] = {0.f, 0.f, 0.f, 0.f};

    for (int kt = 0; kt <= qi; ++kt) {
        const int t0 = kt * 64;
        __syncthreads();
#pragma unroll
        for (int i = 0; i < 2; ++i) {
            *(u16x8*)&Ks[sr[i] * 72 + sc[i] * 8] = kpre[i];
            *(u16x8*)&Vs[sr[i] * 72 + sc[i] * 8] = vpre[i];
        }
        __syncthreads();
        if (kt < qi) {
            const int t1 = t0 + 64;
#pragma unroll
            for (int i = 0; i < 2; ++i) {
                kpre[i] = *(const u16x8*)(kbase + (size_t)(t1 + sr[i]) * DD + sc[i] * 8);
                vpre[i] = *(const u16x8*)(vbase + (size_t)sr[i] * SS + t1 + sc[i] * 8);
            }
        }

        // ---- scores: S = (Q/8) @ K^T, 16 rows x 64 cols per wave ----
        f32x4 sfr[4];
#pragma unroll
        for (int ct = 0; ct < 4; ++ct) {
            const bf16x8 b0 = *(const bf16x8*)&Ks[(ct * 16 + ln) * 72 + qd * 8];
            const bf16x8 b1 = *(const bf16x8*)&Ks[(ct * 16 + ln) * 72 + 32 + qd * 8];
            f32x4 t = __builtin_amdgcn_mfma_f32_16x16x32_bf16(
                aq[0], b0, (f32x4){0.f, 0.f, 0.f, 0.f}, 0, 0, 0);
            sfr[ct] = __builtin_amdgcn_mfma_f32_16x16x32_bf16(aq[1], b1, t, 0, 0, 0);
        }

        // ---- causal mask (only the diagonal tile straddles) ----
        if (kt == qi) {
#pragma unroll
            for (int ct = 0; ct < 4; ++ct) {
                const int tg = t0 + ct * 16 + ln;
#pragma unroll
                for (int r = 0; r < 4; ++r) {
                    const int qg = q0 + w * 16 + qd * 4 + r;
                    if (tg > qg) sfr[ct][r] = -1e30f;
                }
            }
        }

        // ---- online softmax (registers + 16-lane shuffles) ----
        float rmax[4], alpha[4], rsum[4];
#pragma unroll
        for (int r = 0; r < 4; ++r)
            rmax[r] = fmaxf(fmaxf(sfr[0][r], sfr[1][r]), fmaxf(sfr[2][r], sfr[3][r]));
#pragma unroll
        for (int st = 1; st <= 8; st <<= 1)
#pragma unroll
            for (int r = 0; r < 4; ++r)
                rmax[r] = fmaxf(rmax[r], __shfl_xor(rmax[r], st));
#pragma unroll
        for (int r = 0; r < 4; ++r) {
            const float mn = fmaxf(m_r[r], rmax[r]);
            alpha[r] = __expf(m_r[r] - mn);
            m_r[r] = mn;
        }
#pragma unroll
        for (int ct = 0; ct < 4; ++ct)
#pragma unroll
            for (int r = 0; r < 4; ++r)
                sfr[ct][r] = __expf(sfr[ct][r] - m_r[r]);
#pragma unroll
        for (int r = 0; r < 4; ++r)
            rsum[r] = (sfr[0][r] + sfr[1][r]) + (sfr[2][r] + sfr[3][r]);
#pragma unroll
        for (int st = 1; st <= 8; st <<= 1)
#pragma unroll
            for (int r = 0; r < 4; ++r)
                rsum[r] += __shfl_xor(rsum[r], st);
#pragma unroll
        for (int r = 0; r < 4; ++r)
            l_r[r] = l_r[r] * alpha[r] + rsum[r];

        // ---- P: C-layout regs -> LDS (bf16) -> A-layout frags ----
#pragma unroll
        for (int ct = 0; ct < 4; ++ct)
#pragma unroll
            for (int r = 0; r < 4; ++r)
                Ps[(w * 16 + qd * 4 + r) * 72 + ct * 16 + ln] = f2bf_rne(sfr[ct][r]);
        const bf16x8 ap0 = *(const bf16x8*)&Ps[(w * 16 + ln) * 72 + qd * 8];
        const bf16x8 ap1 = *(const bf16x8*)&Ps[(w * 16 + ln) * 72 + 32 + qd * 8];

        // ---- rescale O, then O += P @ V ----
#pragma unroll
        for (int et = 0; et < 4; ++et)
#pragma unroll
            for (int r = 0; r < 4; ++r)
                oacc[et][r] *= alpha[r];
#pragma unroll
        for (int et = 0; et < 4; ++et) {
            const bf16x8 v0 = *(const bf16x8*)&Vs[(et * 16 + ln) * 72 + qd * 8];
            const bf16x8 v1 = *(const bf16x8*)&Vs[(et * 16 + ln) * 72 + 32 + qd * 8];
            oacc[et] = __builtin_amdgcn_mfma_f32_16x16x32_bf16(ap0, v0, oacc[et], 0, 0, 0);
            oacc[et] = __builtin_amdgcn_mfma_f32_16x16x32_bf16(ap1, v1, oacc[et], 0, 0, 0);
        }
    }

    // ---- finalize: O /= l, write (B,H,S,64) ----
    float linv[4];
#pragma unroll
    for (int r = 0; r < 4; ++r) linv[r] = 1.0f / l_r[r];
    unsigned short* ob = (unsigned short*)O + (size_t)bh * SS * HD;
#pragma unroll
    for (int et = 0; et < 4; ++et)
#pragma unroll
        for (int r = 0; r < 4; ++r) {
            const int qg = q0 + w * 16 + qd * 4 + r;
            ob[(size_t)qg * HD + et * 16 + ln] = f2bf_rne(oacc[et][r] * linv[r]);
        }
}

// ---------------------------------------------------------------------------
// LayerNorm over D=1024, one block per row. In-place safe.
// ---------------------------------------------------------------------------
template <typename TOUT>
__launch_bounds__(256)
__global__ void ln_kernel(const float* __restrict__ X, TOUT* __restrict__ Y,
                          const float* __restrict__ g, const float* __restrict__ be) {
    const int row = blockIdx.x;
    const int tid = threadIdx.x;
    __shared__ float red[256];

    const float* x = X + (size_t)row * DD;
    float v[4];
#pragma unroll
    for (int i = 0; i < 4; ++i) v[i] = x[tid * 4 + i];

    float s = v[0] + v[1] + v[2] + v[3];
    red[tid] = s;
    __syncthreads();
    for (int off = 128; off > 0; off >>= 1) {
        if (tid < off) red[tid] += red[tid + off];
        __syncthreads();
    }
    const float mu = red[0] * (1.0f / DD);
    __syncthreads();

    float s2 = 0.0f;
#pragma unroll
    for (int i = 0; i < 4; ++i) { const float d = v[i] - mu; s2 += d * d; }
    red[tid] = s2;
    __syncthreads();
    for (int off = 128; off > 0; off >>= 1) {
        if (tid < off) red[tid] += red[tid + off];
        __syncthreads();
    }
    const float rs = rsqrtf(red[0] * (1.0f / DD) + LN_EPS);

#pragma unroll
    for (int i = 0; i < 4; ++i) {
        const int n = tid * 4 + i;
        stf(&Y[(size_t)row * DD + n], (v[i] - mu) * rs * g[n] + be[n]);
    }
}

extern "C" void kernel_launch(void* const* d_in, const int* in_sizes, int n_in,
                              void* d_out, int out_size, void* d_ws, size_t ws_size,
                              hipStream_t stream) {
    const float* x = (const float*)d_in[0];
    const float* Wq = (const float*)d_in[1];
    const float* Wk = (const float*)d_in[2];
    const float* Wv = (const float*)d_in[3];
    const float* Wo = (const float*)d_in[4];
    const float* g1 = (const float*)d_in[5];
    const float* be1 = (const float*)d_in[6];
    const float* w_in = (const float*)d_in[7];
    const float* b_in = (const float*)d_in[8];
    const float* w_out = (const float*)d_in[9];
    const float* b_out = (const float*)d_in[10];
    const float* g2 = (const float*)d_in[11];
    const float* be2 = (const float*)d_in[12];
    float* out = (float*)d_out;

    // Workspace (bytes), peak 120 MiB:
    //   [0,16M)    Qb bf16 (B*S,D), pre-scaled by 1/8   -+
    //   [16,32M)   Kb bf16 (B*S,D)                       |-> overlaid by Hd
    //   [32,48M)   VT bf16 (B*D,S)  transposed V         |   (B*S*F) after Wo
    //   [48,64M)   At bf16 (B,H,S,64)                   -+
    //   [64,96M)   X1 fp32
    //   [96,120M)  transposed bf16 weights
    char* wsb = (char*)d_ws;
    const size_t MiB = 1u << 20;
    bf16* Qb = (bf16*)(wsb);
    bf16* Kb = (bf16*)(wsb + 16 * MiB);
    bf16* VT = (bf16*)(wsb + 32 * MiB);
    bf16* At = (bf16*)(wsb + 48 * MiB);
    bf16* Hd = (bf16*)(wsb);
    float* X1 = (float*)(wsb + 64 * MiB);
    bf16* WqT = (bf16*)(wsb + 96 * MiB);
    bf16* WkT = (bf16*)(wsb + 98 * MiB);
    bf16* WvT = (bf16*)(wsb + 100 * MiB);
    bf16* WoT = (bf16*)(wsb + 102 * MiB);
    bf16* w_inT = (bf16*)(wsb + 104 * MiB);
    bf16* w_outT = (bf16*)(wsb + 112 * MiB);
    (void)ws_size;

    const int M = BB * SS;  // 8192
    dim3 blk(256);

    // ---- Pre-transpose weights to bf16 N x K ----
    tr_f32_bf16<<<dim3(2, 32, 16), blk, 0, stream>>>(Wq, WqT, DD, HD);
    tr_f32_bf16<<<dim3(2, 32, 16), blk, 0, stream>>>(Wk, WkT, DD, HD);
    tr_f32_bf16<<<dim3(2, 32, 16), blk, 0, stream>>>(Wv, WvT, DD, HD);
    tr_f32_bf16<<<dim3(32, 32, 1), blk, 0, stream>>>(Wo, WoT, DD, DD);
    tr_f32_bf16<<<dim3(128, 32, 1), blk, 0, stream>>>(w_in, w_inT, DD, FF);
    tr_f32_bf16<<<dim3(32, 128, 1), blk, 0, stream>>>(w_out, w_outT, FF, DD);

    // ---- QKV projections ----
    mfma_gemm<float, bf16, 0><<<dim3(DD / 128, M / 128), blk, 0, stream>>>(
        x, WqT, Qb, nullptr, nullptr, M, DD, DD, 0.125f);  // Q pre-scaled 1/sqrt(64)
    mfma_gemm<float, bf16, 0><<<dim3(DD / 128, M / 128), blk, 0, stream>>>(
        x, WkT, Kb, nullptr, nullptr, M, DD, DD, 1.0f);
    mfma_gemm<float, bf16, 4><<<dim3(DD / 128, M / 128), blk, 0, stream>>>(
        x, WvT, VT, nullptr, nullptr, M, DD, DD, 1.0f);    // V written transposed

    // ---- MFMA causal flash attention ----
    attn_mfma<<<dim3(BB * HH, SS / 64), blk, 0, stream>>>(Qb, Kb, VT, At);

    // ---- attn(view) @ Wo + x -> X1 fp32 ----
    mfma_gemm<bf16, float, 1><<<dim3(DD / 128, M / 128), blk, 0, stream>>>(
        At, WoT, X1, nullptr, x, M, DD, DD, 1.0f);
    ln_kernel<float><<<dim3(M), blk, 0, stream>>>(X1, X1, g1, be1);

    // ---- FFN1: relu(X1 @ w_in + b_in) -> Hd bf16 ----
    mfma_gemm<float, bf16, 2><<<dim3(FF / 128, M / 128), blk, 0, stream>>>(
        X1, w_inT, Hd, b_in, nullptr, M, FF, DD, 1.0f);

    // ---- FFN2: Hd @ w_out + b_out + X1 -> X1 (in-place) ----
    mfma_gemm<bf16, float, 3><<<dim3(DD / 128, M / 128), blk, 0, stream>>>(
        Hd, w_outT, X1, b_out, X1, M, DD, FF, 1.0f);

    // ---- LN2 -> fp32 out ----
    ln_kernel<float><<<dim3(M), blk, 0, stream>>>(X1, out, g2, be2);
}